// Round 12
// baseline (322.492 us; speedup 1.0000x reference)
//
#include <hip/hip_runtime.h>
#include <math.h>

#define NG 6
#define KD 40
#define CB 1024
#define NB 32
#define TP 2000
#define RPB 128              // rows per block (4 waves x 32, gg-paired)
#define THREADS 256
#define NBLK 500             // 64000 / 128
#define ZN 480000
#define ZG 80000
#define EPS_D 0.1f           // widened: covers dropped el.x term (sigma~0.01, 10 sigma)
#define PKH_G 49152          // shorts per group (32 tiles * 1536, hi-only)
#define PKH_T 1536           // shorts per tile
#define CHS 6144             // shorts per chunk (4 tiles)
#define NCH 8                // chunks

typedef __attribute__((ext_vector_type(8))) short bf16x8;
typedef __attribute__((ext_vector_type(16))) float f32x16;

__device__ __forceinline__ unsigned short bf16rne(float v) {
  unsigned u = __float_as_uint(v);
  return (unsigned short)((u + 0x7FFFu + ((u >> 16) & 1u)) >> 16);
}
__device__ __forceinline__ float bf16val(unsigned short h) {
  return __uint_as_float(((unsigned)h) << 16);
}
__device__ __forceinline__ void bf16split(float v, unsigned short& h, unsigned short& l) {
  h = bf16rne(v);
  l = bf16rne(v - bf16val(h));
}
__device__ __forceinline__ bf16x8 ldfrag16(const unsigned short* p) {
  union { uint4 q; bf16x8 v; } u;
  u.q = *(const uint4*)p;
  return u.v;
}
__device__ __forceinline__ void gload_lds16(const void* g, void* l) {
  __builtin_amdgcn_global_load_lds(
      (const __attribute__((address_space(1))) unsigned int*)g,
      (__attribute__((address_space(3))) unsigned int*)l, 16, 0, 0);
}

// ---- prep: et[g][c][k] fp32; np-exact ||e||^2; fragment-ordered bf16 HI pack
__global__ void prep_kernel(const float* __restrict__ emb, float* __restrict__ et,
                            float* __restrict__ e2, unsigned short* __restrict__ epackh) {
  int c = blockIdx.x * blockDim.x + threadIdx.x;
  int g = blockIdx.y;
  if (c >= CB) return;
  const float* eg = emb + (size_t)g * KD * CB;
  float ev[KD];
  float* o = et + ((size_t)g * CB + c) * KD;
  float s = 0.f;
#pragma unroll
  for (int k = 0; k < KD; ++k) {
    float v = eg[k * CB + c];
    ev[k] = v;
    o[k] = v;
    s = __fadd_rn(s, __fmul_rn(v, v));   // np-exact serial unfused
  }
  e2[g * CB + c] = s;

  float sv = 0.5f * s;                    // 3-way bf16 split of the seed
  unsigned short p0 = bf16rne(sv);
  float v1 = sv - bf16val(p0);
  unsigned short p1 = bf16rne(v1);
  unsigned short p2 = bf16rne(v1 - bf16val(p1));

  int tile = c >> 5, j32 = c & 31;
  unsigned short* tb = epackh + (size_t)g * PKH_G + (size_t)tile * PKH_T;
#pragma unroll
  for (int s2 = 0; s2 < 3; ++s2)
#pragma unroll
    for (int gg = 0; gg < 2; ++gg) {
      union { uint4 q; unsigned short sh[8]; } uh;
#pragma unroll
      for (int j = 0; j < 8; ++j) {
        int k = s2 * 16 + gg * 8 + j;
        if (k < KD) {
          unsigned short h, l;
          bf16split(ev[k], h, l);
          uh.sh[j] = h;
        } else {
          uh.sh[j] = (k == 40) ? p0 : (k == 41) ? p1 : (k == 42) ? p2 : (unsigned short)0;
        }
      }
      *(uint4*)(tb + ((size_t)(s2 * 2 + gg) * 32 + j32) * 8) = uh.q;
    }
}

__device__ __forceinline__ float npd_calc(const float* __restrict__ x,
                                          const float* __restrict__ ef,
                                          float e2c, float x2np) {
  float dot = 0.f;
#pragma unroll
  for (int k = 0; k < KD; ++k) dot = __fadd_rn(dot, __fmul_rn(x[k], ef[k]));
  return __fadd_rn(__fsub_rn(x2np, __fadd_rn(dot, dot)), e2c);
}

__global__ __launch_bounds__(THREADS, 4) void vq_kernel(
    const float* __restrict__ z, const float* __restrict__ et,
    const float* __restrict__ e2, const unsigned short* __restrict__ epackh,
    float* __restrict__ out, float* __restrict__ partials) {
  const int g = blockIdx.y;
  const int bb = blockIdx.x;
  const int tid = threadIdx.x;
  const int lane = tid & 63;
  const int gg = lane >> 5;
  const int j32 = lane & 31;
  const int wid = tid >> 6;
  const int rowloc = wid * 32 + j32;
  const int rid = bb * RPB + rowloc;
  const int n = rid / TP;
  const int tt = rid - n * TP;

  const float* etg = et + (size_t)g * CB * KD;
  const float* e2g = e2 + g * CB;
  const unsigned short* egrp = epackh + (size_t)g * PKH_G;

  __shared__ __align__(16) unsigned short sbuf[2][CHS];
  __shared__ float r0s[THREADS], r1s[THREADS];

  // ---- stage chunk 0 immediately (DMA overlaps the x prologue)
#define STAGE(B, CH) { \
    const unsigned short* gsrc = egrp + (size_t)(CH) * CHS + wid * 512 + lane * 8; \
    unsigned short* lb = &sbuf[B][wid * 512]; \
    gload_lds16(gsrc, lb); \
    gload_lds16(gsrc + 2048, lb + 2048); \
    gload_lds16(gsrc + 4096, lb + 4096); }
  STAGE(0, 0)

  // ---- row x in registers; x2np (numpy pairwise-8, verified r6)
  const float* zp = z + (size_t)n * ZN + (size_t)g * ZG + tt;
  float x[KD];
#pragma unroll
  for (int k = 0; k < KD; ++k) x[k] = zp[(size_t)k * TP];
  float x2np;
  {
    float r[8];
#pragma unroll
    for (int j = 0; j < 8; ++j) r[j] = __fmul_rn(x[j], x[j]);
#pragma unroll
    for (int i = 8; i < KD; i += 8)
#pragma unroll
      for (int j = 0; j < 8; ++j)
        r[j] = __fadd_rn(r[j], __fmul_rn(x[i + j], x[i + j]));
    x2np = __fadd_rn(__fadd_rn(__fadd_rn(r[0], r[1]), __fadd_rn(r[2], r[3])),
                     __fadd_rn(__fadd_rn(r[4], r[5]), __fadd_rn(r[6], r[7])));
  }

  // ---- B fragments from -x, static per-gg k-slices (verified r9/r10/r11)
  bf16x8 xh[3], xl[3];
#define PACK8(DH, DL, B0) { \
    union { unsigned short s[8]; bf16x8 v; } uh, ul; \
    _Pragma("unroll") \
    for (int j = 0; j < 8; ++j) { \
      unsigned short h, l; bf16split(-x[(B0) + j], h, l); \
      uh.s[j] = h; ul.s[j] = l; } \
    DH = uh.v; DL = ul.v; }
  if (gg == 0) {
    PACK8(xh[0], xl[0], 0)
    PACK8(xh[1], xl[1], 16)
    PACK8(xh[2], xl[2], 32)
  } else {
    PACK8(xh[0], xl[0], 8)
    PACK8(xh[1], xl[1], 24)
    union { unsigned short s[8]; bf16x8 v; } uh;
#pragma unroll
    for (int j = 0; j < 8; ++j) uh.s[j] = (j < 3) ? (unsigned short)0x3F80 : (unsigned short)0;
    xh[2] = uh.v;
    union { unsigned short s[8]; bf16x8 v; } uz;
#pragma unroll
    for (int j = 0; j < 8; ++j) uz.s[j] = 0;
    xl[2] = uz.v;
  }
#undef PACK8

  f32x16 zacc;
#pragma unroll
  for (int i = 0; i < 16; ++i) zacc[i] = 0.f;

  float thr = -INFINITY;   // seeded at tile 0; sc < thr <=> 2sc + x2 < best_d + EPS
  float best_d = INFINITY;
  int best_i = CB;

#define UPDATE(DV, CV) { \
    bool bt = (DV) < best_d || ((DV) == best_d && (CV) < best_i); \
    if (bt) { best_d = (DV); best_i = (CV); thr = (best_d + EPS_D - x2np) * 0.5f; } }

#define TRACK(AV, TILE, SEED) { \
    if (SEED) { \
      float m = AV[0]; int mi = 0; \
      _Pragma("unroll") \
      for (int i = 1; i < 16; ++i) { if (AV[i] < m) { m = AV[i]; mi = i; } } \
      int c0 = (TILE) * 32 + 8 * (mi >> 2) + 4 * gg + (mi & 3); \
      float d0 = npd_calc(x, etg + (size_t)c0 * KD, e2g[c0], x2np); \
      UPDATE(d0, c0) \
    } \
    float gm0 = fminf(fminf(AV[0], AV[1]), fminf(AV[2], AV[3])); \
    float gm1 = fminf(fminf(AV[4], AV[5]), fminf(AV[6], AV[7])); \
    float gm2 = fminf(fminf(AV[8], AV[9]), fminf(AV[10], AV[11])); \
    float gm3 = fminf(fminf(AV[12], AV[13]), fminf(AV[14], AV[15])); \
    if ((gm0 < thr) | (gm1 < thr) | (gm2 < thr) | (gm3 < thr)) { \
      unsigned msk = 0; \
      _Pragma("unroll") \
      for (int i = 0; i < 16; ++i) msk |= (AV[i] < thr) ? (1u << i) : 0u; \
      while (msk) { \
        int i = __ffs(msk) - 1; \
        msk &= msk - 1; \
        int c = (TILE) * 32 + 8 * (i >> 2) + 4 * gg + (i & 3); \
        float dd = npd_calc(x, etg + (size_t)c * KD, e2g[c], x2np); \
        UPDATE(dd, c) \
      } \
    } }

#define COMPUTE_PAIR(T2A, T2B, SEED) { \
    const unsigned short* tba = &sbuf[cur][(T2A) * PKH_T + gg * 256 + j32 * 8]; \
    const unsigned short* tbb = &sbuf[cur][(T2B) * PKH_T + gg * 256 + j32 * 8]; \
    bf16x8 ea0 = ldfrag16(tba); \
    bf16x8 ea1 = ldfrag16(tba + 512); \
    bf16x8 ea2 = ldfrag16(tba + 1024); \
    bf16x8 eb0 = ldfrag16(tbb); \
    bf16x8 eb1 = ldfrag16(tbb + 512); \
    bf16x8 eb2 = ldfrag16(tbb + 1024); \
    f32x16 va, vb; \
    va = __builtin_amdgcn_mfma_f32_32x32x16_bf16(ea0, xh[0], zacc, 0, 0, 0); \
    vb = __builtin_amdgcn_mfma_f32_32x32x16_bf16(eb0, xh[0], zacc, 0, 0, 0); \
    va = __builtin_amdgcn_mfma_f32_32x32x16_bf16(ea0, xl[0], va, 0, 0, 0); \
    vb = __builtin_amdgcn_mfma_f32_32x32x16_bf16(eb0, xl[0], vb, 0, 0, 0); \
    va = __builtin_amdgcn_mfma_f32_32x32x16_bf16(ea1, xh[1], va, 0, 0, 0); \
    vb = __builtin_amdgcn_mfma_f32_32x32x16_bf16(eb1, xh[1], vb, 0, 0, 0); \
    va = __builtin_amdgcn_mfma_f32_32x32x16_bf16(ea1, xl[1], va, 0, 0, 0); \
    vb = __builtin_amdgcn_mfma_f32_32x32x16_bf16(eb1, xl[1], vb, 0, 0, 0); \
    va = __builtin_amdgcn_mfma_f32_32x32x16_bf16(ea2, xh[2], va, 0, 0, 0); \
    vb = __builtin_amdgcn_mfma_f32_32x32x16_bf16(eb2, xh[2], vb, 0, 0, 0); \
    va = __builtin_amdgcn_mfma_f32_32x32x16_bf16(ea2, xl[2], va, 0, 0, 0); \
    vb = __builtin_amdgcn_mfma_f32_32x32x16_bf16(eb2, xl[2], vb, 0, 0, 0); \
    TRACK(va, ch * 4 + (T2A), SEED) \
    TRACK(vb, ch * 4 + (T2B), false) }

  int cur = 0;
#pragma unroll 1
  for (int ch = 0; ch < NCH; ++ch) {
    if (ch + 1 < NCH) {
      STAGE(cur ^ 1, ch + 1)
      asm volatile("s_waitcnt vmcnt(3)" ::: "memory");  // chunk ch done; next 3 in flight
    } else {
      asm volatile("s_waitcnt vmcnt(0)" ::: "memory");
    }
    __builtin_amdgcn_s_barrier();
    COMPUTE_PAIR(0, 1, ch == 0)
    COMPUTE_PAIR(2, 3, false)
    __builtin_amdgcn_s_barrier();   // all waves done reading before next overwrite
    cur ^= 1;
  }

  // merge the two k-half lanes of each row ((d,c) ordering, np first-min)
  {
    float od = __shfl_xor(best_d, 32);
    int oi = __shfl_xor(best_i, 32);
    if (od < best_d || (od == best_d && oi < best_i)) { best_d = od; best_i = oi; }
  }

  // ---- epilogue: STE write + loss partial, static k-halves per gg
  const float4* eb4 = (const float4*)(etg + (size_t)best_i * KD);
  float* op = out + (size_t)n * ZN + (size_t)g * ZG + tt;
  float ls = 0.f;
  if (gg == 0) {
#pragma unroll
    for (int p = 0; p < 5; ++p) {
      float4 v = eb4[p];
      int k = 4 * p;
      float d0 = __fsub_rn(v.x, x[k + 0]); ls = fmaf(d0, d0, ls); op[(size_t)(k + 0) * TP] = __fadd_rn(x[k + 0], d0);
      float d1 = __fsub_rn(v.y, x[k + 1]); ls = fmaf(d1, d1, ls); op[(size_t)(k + 1) * TP] = __fadd_rn(x[k + 1], d1);
      float d2 = __fsub_rn(v.z, x[k + 2]); ls = fmaf(d2, d2, ls); op[(size_t)(k + 2) * TP] = __fadd_rn(x[k + 2], d2);
      float d3 = __fsub_rn(v.w, x[k + 3]); ls = fmaf(d3, d3, ls); op[(size_t)(k + 3) * TP] = __fadd_rn(x[k + 3], d3);
    }
  } else {
#pragma unroll
    for (int p = 5; p < 10; ++p) {
      float4 v = eb4[p];
      int k = 4 * p;
      float d0 = __fsub_rn(v.x, x[k + 0]); ls = fmaf(d0, d0, ls); op[(size_t)(k + 0) * TP] = __fadd_rn(x[k + 0], d0);
      float d1 = __fsub_rn(v.y, x[k + 1]); ls = fmaf(d1, d1, ls); op[(size_t)(k + 1) * TP] = __fadd_rn(x[k + 1], d1);
      float d2 = __fsub_rn(v.z, x[k + 2]); ls = fmaf(d2, d2, ls); op[(size_t)(k + 2) * TP] = __fadd_rn(x[k + 2], d2);
      float d3 = __fsub_rn(v.w, x[k + 3]); ls = fmaf(d3, d3, ls); op[(size_t)(k + 3) * TP] = __fadd_rn(x[k + 3], d3);
    }
  }

  // ---- deterministic segmented block reduce (block straddles <=1 n boundary)
  const int n_lo = (bb * RPB) / TP;
  r0s[tid] = (n == n_lo) ? ls : 0.f;
  r1s[tid] = (n == n_lo) ? 0.f : ls;
  __syncthreads();
  for (int s = THREADS / 2; s > 0; s >>= 1) {
    if (tid < s) {
      r0s[tid] += r0s[tid + s];
      r1s[tid] += r1s[tid + s];
    }
    __syncthreads();
  }
  if (tid == 0) {
    partials[((size_t)g * NBLK + bb) * 2 + 0] = r0s[0];
    partials[((size_t)g * NBLK + bb) * 2 + 1] = r1s[0];
  }
}

// ---- final: fixed-order reduction of per-block partials -> vq_loss[n]
__global__ void loss_kernel(const float* __restrict__ partials,
                            float* __restrict__ vq) {
  int n = threadIdx.x;
  if (n >= NB) return;
  float acc = 0.f;
  for (int g = 0; g < NG; ++g) {
    float s = 0.f;
    int b0 = (n * TP) / RPB;
    int b1 = ((n + 1) * TP - 1) / RPB;
    for (int b = b0; b <= b1; ++b) {
      int n_lo = (b * RPB) / TP;
      s += partials[((size_t)g * NBLK + b) * 2 + ((n == n_lo) ? 0 : 1)];
    }
    acc += 0.25f * (s / 80000.0f);
  }
  vq[n] = acc / 6.0f;
}

extern "C" void kernel_launch(void* const* d_in, const int* in_sizes, int n_in,
                              void* d_out, int out_size, void* d_ws, size_t ws_size,
                              hipStream_t stream) {
  const float* z = (const float*)d_in[0];
  const float* emb = (const float*)d_in[1];
  float* out = (float*)d_out;

  float* et = (float*)d_ws;                          // 983,040 B
  float* e2 = et + (size_t)NG * CB * KD;             // 24,576 B
  float* partials = e2 + (size_t)NG * CB;            // 24,000 B
  unsigned short* epackh = (unsigned short*)((char*)d_ws + 1031680);  // 589,824 B

  prep_kernel<<<dim3(CB / 256, NG), 256, 0, stream>>>(emb, et, e2, epackh);
  vq_kernel<<<dim3(NBLK, NG), THREADS, 0, stream>>>(z, et, e2, epackh, out, partials);
  loss_kernel<<<1, 64, 0, stream>>>(partials, out + (size_t)NB * 60 * 8000);
}

// Round 13
// 222.802 us; speedup vs baseline: 1.4474x; 1.4474x over previous
//
#include <hip/hip_runtime.h>
#include <math.h>

#define NG 6
#define KD 40
#define CB 1024
#define NB 32
#define TP 2000
#define RPB 128              // rows per block (4 waves x 32, gg-paired)
#define THREADS 256
#define NBLK 500             // 64000 / 128
#define ZN 480000
#define ZG 80000
#define BAND_D 6e-3f         // |approx_dist - np_dist| bound with >=2x margin
#define PK_G 98304           // shorts per group (32 tiles * 3072, hi+lo)
#define PK_T 3072            // shorts per tile
#define CHS 6144             // shorts per chunk (2 tiles)
#define NCH 16               // chunks

typedef __attribute__((ext_vector_type(8))) short bf16x8;
typedef __attribute__((ext_vector_type(16))) float f32x16;

__device__ __forceinline__ unsigned short bf16rne(float v) {
  unsigned u = __float_as_uint(v);
  return (unsigned short)((u + 0x7FFFu + ((u >> 16) & 1u)) >> 16);
}
__device__ __forceinline__ float bf16val(unsigned short h) {
  return __uint_as_float(((unsigned)h) << 16);
}
__device__ __forceinline__ void bf16split(float v, unsigned short& h, unsigned short& l) {
  h = bf16rne(v);
  l = bf16rne(v - bf16val(h));
}
__device__ __forceinline__ bf16x8 ldfrag16(const unsigned short* p) {
  union { uint4 q; bf16x8 v; } u;
  u.q = *(const uint4*)p;
  return u.v;
}
__device__ __forceinline__ void gload_lds16(const void* g, void* l) {
  __builtin_amdgcn_global_load_lds(
      (const __attribute__((address_space(1))) unsigned int*)g,
      (__attribute__((address_space(3))) unsigned int*)l, 16, 0, 0);
}

// ---- prep: et[g][c][k] fp32; np-exact ||e||^2; fragment-ordered bf16 hi/lo pack (r11)
__global__ void prep_kernel(const float* __restrict__ emb, float* __restrict__ et,
                            float* __restrict__ e2, unsigned short* __restrict__ epack) {
  int c = blockIdx.x * blockDim.x + threadIdx.x;
  int g = blockIdx.y;
  if (c >= CB) return;
  const float* eg = emb + (size_t)g * KD * CB;
  float ev[KD];
  float* o = et + ((size_t)g * CB + c) * KD;
  float s = 0.f;
#pragma unroll
  for (int k = 0; k < KD; ++k) {
    float v = eg[k * CB + c];
    ev[k] = v;
    o[k] = v;
    s = __fadd_rn(s, __fmul_rn(v, v));   // np-exact serial unfused
  }
  e2[g * CB + c] = s;

  float sv = 0.5f * s;                    // 3-way bf16 split of the seed
  unsigned short p0 = bf16rne(sv);
  float v1 = sv - bf16val(p0);
  unsigned short p1 = bf16rne(v1);
  unsigned short p2 = bf16rne(v1 - bf16val(p1));

  int tile = c >> 5, j32 = c & 31;
  unsigned short* tb = epack + (size_t)g * PK_G + (size_t)tile * PK_T;
#pragma unroll
  for (int s2 = 0; s2 < 3; ++s2)
#pragma unroll
    for (int gg = 0; gg < 2; ++gg) {
      union { uint4 q; unsigned short sh[8]; } uh, ul;
#pragma unroll
      for (int j = 0; j < 8; ++j) {
        int k = s2 * 16 + gg * 8 + j;
        if (k < KD) {
          bf16split(ev[k], uh.sh[j], ul.sh[j]);
        } else {
          uh.sh[j] = (k == 40) ? p0 : (k == 41) ? p1 : (k == 42) ? p2 : (unsigned short)0;
          ul.sh[j] = 0;
        }
      }
      unsigned short* ph = tb + ((size_t)(s2 * 2 + gg) * 32 + j32) * 8;
      *(uint4*)ph = uh.q;
      *(uint4*)(ph + 1536) = ul.q;
    }
}

__device__ __forceinline__ float npd_calc(const float* __restrict__ x,
                                          const float* __restrict__ ef,
                                          float e2c, float x2np) {
  float dot = 0.f;
#pragma unroll
  for (int k = 0; k < KD; ++k) dot = __fadd_rn(dot, __fmul_rn(x[k], ef[k]));
  return __fadd_rn(__fsub_rn(x2np, __fadd_rn(dot, dot)), e2c);
}

__global__ __launch_bounds__(THREADS, 4) void vq_kernel(
    const float* __restrict__ z, const float* __restrict__ et,
    const float* __restrict__ e2, const unsigned short* __restrict__ epack,
    float* __restrict__ out, float* __restrict__ partials) {
  const int g = blockIdx.y;
  const int bb = blockIdx.x;
  const int tid = threadIdx.x;
  const int lane = tid & 63;
  const int gg = lane >> 5;
  const int j32 = lane & 31;
  const int wid = tid >> 6;
  const int rowloc = wid * 32 + j32;
  const int rid = bb * RPB + rowloc;
  const int n = rid / TP;
  const int tt = rid - n * TP;

  const float* etg = et + (size_t)g * CB * KD;
  const float* e2g = e2 + g * CB;
  const unsigned short* egrp = epack + (size_t)g * PK_G;

  __shared__ __align__(16) unsigned short sbuf[2][CHS];
  __shared__ float r0s[THREADS], r1s[THREADS];

#define STAGE(B, CH) { \
    const unsigned short* gsrc = egrp + (size_t)(CH) * CHS + wid * 512 + lane * 8; \
    unsigned short* lb = &sbuf[B][wid * 512]; \
    gload_lds16(gsrc, lb); \
    gload_lds16(gsrc + 2048, lb + 2048); \
    gload_lds16(gsrc + 4096, lb + 4096); }
  STAGE(0, 0)

  // ---- row x in registers; x2np (numpy pairwise-8, verified r6)
  const float* zp = z + (size_t)n * ZN + (size_t)g * ZG + tt;
  float x[KD];
#pragma unroll
  for (int k = 0; k < KD; ++k) x[k] = zp[(size_t)k * TP];
  float x2np;
  {
    float r[8];
#pragma unroll
    for (int j = 0; j < 8; ++j) r[j] = __fmul_rn(x[j], x[j]);
#pragma unroll
    for (int i = 8; i < KD; i += 8)
#pragma unroll
      for (int j = 0; j < 8; ++j)
        r[j] = __fadd_rn(r[j], __fmul_rn(x[i + j], x[i + j]));
    x2np = __fadd_rn(__fadd_rn(__fadd_rn(r[0], r[1]), __fadd_rn(r[2], r[3])),
                     __fadd_rn(__fadd_rn(r[4], r[5]), __fadd_rn(r[6], r[7])));
  }

  // ---- B fragments from -x, static per-gg k-slices (verified r9-r12)
  bf16x8 xh[3], xl[3];
#define PACK8(DH, DL, B0) { \
    union { unsigned short s[8]; bf16x8 v; } uh, ul; \
    _Pragma("unroll") \
    for (int j = 0; j < 8; ++j) { \
      unsigned short h, l; bf16split(-x[(B0) + j], h, l); \
      uh.s[j] = h; ul.s[j] = l; } \
    DH = uh.v; DL = ul.v; }
  if (gg == 0) {
    PACK8(xh[0], xl[0], 0)
    PACK8(xh[1], xl[1], 16)
    PACK8(xh[2], xl[2], 32)
  } else {
    PACK8(xh[0], xl[0], 8)
    PACK8(xh[1], xl[1], 24)
    union { unsigned short s[8]; bf16x8 v; } uh;
#pragma unroll
    for (int j = 0; j < 8; ++j) uh.s[j] = (j < 3) ? (unsigned short)0x3F80 : (unsigned short)0;
    xh[2] = uh.v;
    union { unsigned short s[8]; bf16x8 v; } uz;
#pragma unroll
    for (int j = 0; j < 8; ++j) uz.s[j] = 0;
    xl[2] = uz.v;
  }
#undef PACK8

  f32x16 zacc;
#pragma unroll
  for (int i = 0; i < 16; ++i) zacc[i] = 0.f;

  // ---- approx top-3 tracking (score space), NO rescores in the loop
  float d1 = INFINITY, d2 = INFINITY, d3 = INFINITY;
  int i1 = 0, i2 = 0, i3 = 0;

#define INS3(V, C) { \
    bool u1 = (V) < d1, u2 = (V) < d2, u3 = (V) < d3; \
    d3 = u2 ? d2 : (u3 ? (V) : d3); i3 = u2 ? i2 : (u3 ? (C) : i3); \
    d2 = u1 ? d1 : (u2 ? (V) : d2); i2 = u1 ? i1 : (u2 ? (C) : i2); \
    d1 = u1 ? (V) : d1;             i1 = u1 ? (C) : i1; }

#define TRACK(AV, TILE) { \
    float gm0 = fminf(fminf(AV[0], AV[1]), fminf(AV[2], AV[3])); \
    float gm1 = fminf(fminf(AV[4], AV[5]), fminf(AV[6], AV[7])); \
    float gm2 = fminf(fminf(AV[8], AV[9]), fminf(AV[10], AV[11])); \
    float gm3 = fminf(fminf(AV[12], AV[13]), fminf(AV[14], AV[15])); \
    float tmin = fminf(fminf(gm0, gm1), fminf(gm2, gm3)); \
    if (tmin < d3) { \
      int cb = (TILE) * 32 + 4 * gg; \
      if (gm0 < d3) { INS3(AV[0], cb + 0) INS3(AV[1], cb + 1) INS3(AV[2], cb + 2) INS3(AV[3], cb + 3) } \
      if (gm1 < d3) { INS3(AV[4], cb + 8) INS3(AV[5], cb + 9) INS3(AV[6], cb + 10) INS3(AV[7], cb + 11) } \
      if (gm2 < d3) { INS3(AV[8], cb + 16) INS3(AV[9], cb + 17) INS3(AV[10], cb + 18) INS3(AV[11], cb + 19) } \
      if (gm3 < d3) { INS3(AV[12], cb + 24) INS3(AV[13], cb + 25) INS3(AV[14], cb + 26) INS3(AV[15], cb + 27) } \
    } }

#define COMPUTE_TILE(T2, TILE) { \
    const unsigned short* tb = &sbuf[cur][(T2) * PK_T + lane * 8]; \
    bf16x8 eh0 = ldfrag16(tb); \
    bf16x8 eh1 = ldfrag16(tb + 512); \
    bf16x8 eh2 = ldfrag16(tb + 1024); \
    bf16x8 el0 = ldfrag16(tb + 1536); \
    bf16x8 el1 = ldfrag16(tb + 2048); \
    bf16x8 el2 = ldfrag16(tb + 2560); \
    f32x16 a; \
    a = __builtin_amdgcn_mfma_f32_32x32x16_bf16(eh0, xh[0], zacc, 0, 0, 0); \
    a = __builtin_amdgcn_mfma_f32_32x32x16_bf16(eh0, xl[0], a, 0, 0, 0); \
    a = __builtin_amdgcn_mfma_f32_32x32x16_bf16(el0, xh[0], a, 0, 0, 0); \
    a = __builtin_amdgcn_mfma_f32_32x32x16_bf16(eh1, xh[1], a, 0, 0, 0); \
    a = __builtin_amdgcn_mfma_f32_32x32x16_bf16(eh1, xl[1], a, 0, 0, 0); \
    a = __builtin_amdgcn_mfma_f32_32x32x16_bf16(el1, xh[1], a, 0, 0, 0); \
    a = __builtin_amdgcn_mfma_f32_32x32x16_bf16(eh2, xh[2], a, 0, 0, 0); \
    a = __builtin_amdgcn_mfma_f32_32x32x16_bf16(eh2, xl[2], a, 0, 0, 0); \
    a = __builtin_amdgcn_mfma_f32_32x32x16_bf16(el2, xh[2], a, 0, 0, 0); \
    TRACK(a, TILE) }

  int cur = 0;
#pragma unroll 1
  for (int ch = 0; ch < NCH; ++ch) {
    if (ch + 1 < NCH) {
      STAGE(cur ^ 1, ch + 1)
      asm volatile("s_waitcnt vmcnt(3)" ::: "memory");  // chunk ch done; next 3 in flight
    } else {
      asm volatile("s_waitcnt vmcnt(0)" ::: "memory");
    }
    __builtin_amdgcn_s_barrier();
    COMPUTE_TILE(0, ch * 2)
    COMPUTE_TILE(1, ch * 2 + 1)
    __builtin_amdgcn_s_barrier();   // all waves done reading before next overwrite
    cur ^= 1;
  }

  // ---- end phase: approx dists; np-exact rescore ONLY on band ties (batched)
  float dd1 = fmaf(2.f, d1, x2np);
  float dd2 = fmaf(2.f, d2, x2np);
  float dd3 = fmaf(2.f, d3, x2np);
  float bd = dd1;
  int bi = i1;
  bool exact = false;
  {
    bool need2 = dd2 < dd1 + BAND_D;
    bool need3 = dd3 < dd1 + BAND_D;
    if (need2 || need3) {
      int cA = i1;
      int cB = need2 ? i2 : 0x7fffffff;
      int cC = need3 ? i3 : 0x7fffffff;
      int t;
      if (cA > cB) { t = cA; cA = cB; cB = t; }
      if (cB > cC) { t = cB; cB = cC; cC = t; }
      if (cA > cB) { t = cA; cA = cB; cB = t; }
      bd = INFINITY; bi = CB;
      if (cA < CB) { float d = npd_calc(x, etg + (size_t)cA * KD, e2g[cA], x2np); if (d < bd) { bd = d; bi = cA; } }
      if (cB < CB) { float d = npd_calc(x, etg + (size_t)cB * KD, e2g[cB], x2np); if (d < bd) { bd = d; bi = cB; } }
      if (cC < CB) { float d = npd_calc(x, etg + (size_t)cC * KD, e2g[cC], x2np); if (d < bd) { bd = d; bi = cC; } }
      exact = true;
    }
  }
  // cross-half merge: approx compare safe when gap >= BAND; else np-rescore own
  {
    float od = __shfl_xor(bd, 32);
    bool race = fabsf(bd - od) < BAND_D;
    if (race && !exact) bd = npd_calc(x, etg + (size_t)bi * KD, e2g[bi], x2np);
    float od2 = __shfl_xor(bd, 32);
    int oi = __shfl_xor(bi, 32);
    if (od2 < bd || (od2 == bd && oi < bi)) { bd = od2; bi = oi; }
  }

  // ---- epilogue: STE write + loss partial, static k-halves per gg
  const float4* eb4 = (const float4*)(etg + (size_t)bi * KD);
  float* op = out + (size_t)n * ZN + (size_t)g * ZG + tt;
  float ls = 0.f;
  if (gg == 0) {
#pragma unroll
    for (int p = 0; p < 5; ++p) {
      float4 v = eb4[p];
      int k = 4 * p;
      float e0 = __fsub_rn(v.x, x[k + 0]); ls = fmaf(e0, e0, ls); op[(size_t)(k + 0) * TP] = __fadd_rn(x[k + 0], e0);
      float e1 = __fsub_rn(v.y, x[k + 1]); ls = fmaf(e1, e1, ls); op[(size_t)(k + 1) * TP] = __fadd_rn(x[k + 1], e1);
      float e2v = __fsub_rn(v.z, x[k + 2]); ls = fmaf(e2v, e2v, ls); op[(size_t)(k + 2) * TP] = __fadd_rn(x[k + 2], e2v);
      float e3 = __fsub_rn(v.w, x[k + 3]); ls = fmaf(e3, e3, ls); op[(size_t)(k + 3) * TP] = __fadd_rn(x[k + 3], e3);
    }
  } else {
#pragma unroll
    for (int p = 5; p < 10; ++p) {
      float4 v = eb4[p];
      int k = 4 * p;
      float e0 = __fsub_rn(v.x, x[k + 0]); ls = fmaf(e0, e0, ls); op[(size_t)(k + 0) * TP] = __fadd_rn(x[k + 0], e0);
      float e1 = __fsub_rn(v.y, x[k + 1]); ls = fmaf(e1, e1, ls); op[(size_t)(k + 1) * TP] = __fadd_rn(x[k + 1], e1);
      float e2v = __fsub_rn(v.z, x[k + 2]); ls = fmaf(e2v, e2v, ls); op[(size_t)(k + 2) * TP] = __fadd_rn(x[k + 2], e2v);
      float e3 = __fsub_rn(v.w, x[k + 3]); ls = fmaf(e3, e3, ls); op[(size_t)(k + 3) * TP] = __fadd_rn(x[k + 3], e3);
    }
  }

  // ---- deterministic segmented block reduce (block straddles <=1 n boundary)
  const int n_lo = (bb * RPB) / TP;
  r0s[tid] = (n == n_lo) ? ls : 0.f;
  r1s[tid] = (n == n_lo) ? 0.f : ls;
  __syncthreads();
  for (int s = THREADS / 2; s > 0; s >>= 1) {
    if (tid < s) {
      r0s[tid] += r0s[tid + s];
      r1s[tid] += r1s[tid + s];
    }
    __syncthreads();
  }
  if (tid == 0) {
    partials[((size_t)g * NBLK + bb) * 2 + 0] = r0s[0];
    partials[((size_t)g * NBLK + bb) * 2 + 1] = r1s[0];
  }
}

// ---- final: fixed-order reduction of per-block partials -> vq_loss[n]
__global__ void loss_kernel(const float* __restrict__ partials,
                            float* __restrict__ vq) {
  int n = threadIdx.x;
  if (n >= NB) return;
  float acc = 0.f;
  for (int g = 0; g < NG; ++g) {
    float s = 0.f;
    int b0 = (n * TP) / RPB;
    int b1 = ((n + 1) * TP - 1) / RPB;
    for (int b = b0; b <= b1; ++b) {
      int n_lo = (b * RPB) / TP;
      s += partials[((size_t)g * NBLK + b) * 2 + ((n == n_lo) ? 0 : 1)];
    }
    acc += 0.25f * (s / 80000.0f);
  }
  vq[n] = acc / 6.0f;
}

extern "C" void kernel_launch(void* const* d_in, const int* in_sizes, int n_in,
                              void* d_out, int out_size, void* d_ws, size_t ws_size,
                              hipStream_t stream) {
  const float* z = (const float*)d_in[0];
  const float* emb = (const float*)d_in[1];
  float* out = (float*)d_out;

  float* et = (float*)d_ws;                          // 983,040 B
  float* e2 = et + (size_t)NG * CB * KD;             // 24,576 B
  float* partials = e2 + (size_t)NG * CB;            // 24,000 B
  unsigned short* epack = (unsigned short*)((char*)d_ws + 1031680);  // 1,179,648 B

  prep_kernel<<<dim3(CB / 256, NG), 256, 0, stream>>>(emb, et, e2, epack);
  vq_kernel<<<dim3(NBLK, NG), THREADS, 0, stream>>>(z, et, e2, epack, out, partials);
  loss_kernel<<<1, 64, 0, stream>>>(partials, out + (size_t)NB * 60 * 8000);
}

// Round 14
// 205.572 us; speedup vs baseline: 1.5688x; 1.0838x over previous
//
#include <hip/hip_runtime.h>
#include <math.h>

#define NG 6
#define KD 40
#define CB 1024
#define NB 32
#define TP 2000
#define RPB 128              // rows per block (4 waves x 32, gg-paired)
#define THREADS 256
#define NBLK 500             // 64000 / 128
#define ZN 480000
#define ZG 80000
#define BAND_D 6e-3f         // |approx_dist - np_dist| bound with >=2x margin
#define PK_G 98304           // shorts per group (32 tiles * 3072, hi+lo)
#define PK_T 3072            // shorts per tile
#define CHS 6144             // shorts per chunk (2 tiles)
#define NCH 16               // chunks

typedef __attribute__((ext_vector_type(8))) short bf16x8;
typedef __attribute__((ext_vector_type(16))) float f32x16;

__device__ __forceinline__ unsigned short bf16rne(float v) {
  unsigned u = __float_as_uint(v);
  return (unsigned short)((u + 0x7FFFu + ((u >> 16) & 1u)) >> 16);
}
__device__ __forceinline__ float bf16val(unsigned short h) {
  return __uint_as_float(((unsigned)h) << 16);
}
__device__ __forceinline__ void bf16split(float v, unsigned short& h, unsigned short& l) {
  h = bf16rne(v);
  l = bf16rne(v - bf16val(h));
}
__device__ __forceinline__ bf16x8 ldfrag16(const unsigned short* p) {
  union { uint4 q; bf16x8 v; } u;
  u.q = *(const uint4*)p;
  return u.v;
}
__device__ __forceinline__ void gload_lds16(const void* g, void* l) {
  __builtin_amdgcn_global_load_lds(
      (const __attribute__((address_space(1))) unsigned int*)g,
      (__attribute__((address_space(3))) unsigned int*)l, 16, 0, 0);
}

// ---- prep: et[g][c][k] fp32; np-exact ||e||^2; fragment-ordered bf16 hi/lo pack (r11)
__global__ void prep_kernel(const float* __restrict__ emb, float* __restrict__ et,
                            float* __restrict__ e2, unsigned short* __restrict__ epack) {
  int c = blockIdx.x * blockDim.x + threadIdx.x;
  int g = blockIdx.y;
  if (c >= CB) return;
  const float* eg = emb + (size_t)g * KD * CB;
  float ev[KD];
  float* o = et + ((size_t)g * CB + c) * KD;
  float s = 0.f;
#pragma unroll
  for (int k = 0; k < KD; ++k) {
    float v = eg[k * CB + c];
    ev[k] = v;
    o[k] = v;
    s = __fadd_rn(s, __fmul_rn(v, v));   // np-exact serial unfused
  }
  e2[g * CB + c] = s;

  float sv = 0.5f * s;                    // 3-way bf16 split of the seed
  unsigned short p0 = bf16rne(sv);
  float v1 = sv - bf16val(p0);
  unsigned short p1 = bf16rne(v1);
  unsigned short p2 = bf16rne(v1 - bf16val(p1));

  int tile = c >> 5, j32 = c & 31;
  unsigned short* tb = epack + (size_t)g * PK_G + (size_t)tile * PK_T;
#pragma unroll
  for (int s2 = 0; s2 < 3; ++s2)
#pragma unroll
    for (int gg = 0; gg < 2; ++gg) {
      union { uint4 q; unsigned short sh[8]; } uh, ul;
#pragma unroll
      for (int j = 0; j < 8; ++j) {
        int k = s2 * 16 + gg * 8 + j;
        if (k < KD) {
          bf16split(ev[k], uh.sh[j], ul.sh[j]);
        } else {
          uh.sh[j] = (k == 40) ? p0 : (k == 41) ? p1 : (k == 42) ? p2 : (unsigned short)0;
          ul.sh[j] = 0;
        }
      }
      unsigned short* ph = tb + ((size_t)(s2 * 2 + gg) * 32 + j32) * 8;
      *(uint4*)ph = uh.q;
      *(uint4*)(ph + 1536) = ul.q;
    }
}

__device__ __forceinline__ float npd_calc(const float* __restrict__ x,
                                          const float* __restrict__ ef,
                                          float e2c, float x2np) {
  float dot = 0.f;
#pragma unroll
  for (int k = 0; k < KD; ++k) dot = __fadd_rn(dot, __fmul_rn(x[k], ef[k]));
  return __fadd_rn(__fsub_rn(x2np, __fadd_rn(dot, dot)), e2c);
}

__global__ __launch_bounds__(THREADS, 4) void vq_kernel(
    const float* __restrict__ z, const float* __restrict__ et,
    const float* __restrict__ e2, const unsigned short* __restrict__ epack,
    float* __restrict__ out, float* __restrict__ partials) {
  const int g = blockIdx.y;
  const int bb = blockIdx.x;
  const int tid = threadIdx.x;
  const int lane = tid & 63;
  const int gg = lane >> 5;
  const int j32 = lane & 31;
  const int wid = tid >> 6;
  const int rowloc = wid * 32 + j32;
  const int rid = bb * RPB + rowloc;
  const int n = rid / TP;
  const int tt = rid - n * TP;

  const float* etg = et + (size_t)g * CB * KD;
  const float* e2g = e2 + g * CB;
  const unsigned short* egrp = epack + (size_t)g * PK_G;

  __shared__ __align__(16) unsigned short sbuf[2][CHS];
  __shared__ float r0s[THREADS], r1s[THREADS];

#define STAGE(B, CH) { \
    const unsigned short* gsrc = egrp + (size_t)(CH) * CHS + wid * 512 + lane * 8; \
    unsigned short* lb = &sbuf[B][wid * 512]; \
    gload_lds16(gsrc, lb); \
    gload_lds16(gsrc + 2048, lb + 2048); \
    gload_lds16(gsrc + 4096, lb + 4096); }
  STAGE(0, 0)

  // ---- row x in registers; x2np (numpy pairwise-8, verified r6)
  const float* zp = z + (size_t)n * ZN + (size_t)g * ZG + tt;
  float x[KD];
#pragma unroll
  for (int k = 0; k < KD; ++k) x[k] = zp[(size_t)k * TP];
  float x2np;
  {
    float r[8];
#pragma unroll
    for (int j = 0; j < 8; ++j) r[j] = __fmul_rn(x[j], x[j]);
#pragma unroll
    for (int i = 8; i < KD; i += 8)
#pragma unroll
      for (int j = 0; j < 8; ++j)
        r[j] = __fadd_rn(r[j], __fmul_rn(x[i + j], x[i + j]));
    x2np = __fadd_rn(__fadd_rn(__fadd_rn(r[0], r[1]), __fadd_rn(r[2], r[3])),
                     __fadd_rn(__fadd_rn(r[4], r[5]), __fadd_rn(r[6], r[7])));
  }

  // ---- B fragments from -x, static per-gg k-slices (verified r9-r13)
  bf16x8 xh[3], xl[3];
#define PACK8(DH, DL, B0) { \
    union { unsigned short s[8]; bf16x8 v; } uh, ul; \
    _Pragma("unroll") \
    for (int j = 0; j < 8; ++j) { \
      unsigned short h, l; bf16split(-x[(B0) + j], h, l); \
      uh.s[j] = h; ul.s[j] = l; } \
    DH = uh.v; DL = ul.v; }
  if (gg == 0) {
    PACK8(xh[0], xl[0], 0)
    PACK8(xh[1], xl[1], 16)
    PACK8(xh[2], xl[2], 32)
  } else {
    PACK8(xh[0], xl[0], 8)
    PACK8(xh[1], xl[1], 24)
    union { unsigned short s[8]; bf16x8 v; } uh;
#pragma unroll
    for (int j = 0; j < 8; ++j) uh.s[j] = (j < 3) ? (unsigned short)0x3F80 : (unsigned short)0;
    xh[2] = uh.v;
    union { unsigned short s[8]; bf16x8 v; } uz;
#pragma unroll
    for (int j = 0; j < 8; ++j) uz.s[j] = 0;
    xl[2] = uz.v;
  }
#undef PACK8

  f32x16 zacc;
#pragma unroll
  for (int i = 0; i < 16; ++i) zacc[i] = 0.f;

  // ---- branchless tracking: global approx min (d1) + its GROUP base (grp1)
  //      + d2x = min over OTHER groups' group-mins. No walks, no divergence.
  float d1 = INFINITY, d2x = INFINITY;
  int grp1 = 0;

#define TRACKG(AV, TILE) { \
    int cb = (TILE) * 32 + 4 * gg; \
    float g0 = fminf(fminf(fminf(AV[0], AV[1]), AV[2]), AV[3]); \
    float g1 = fminf(fminf(fminf(AV[4], AV[5]), AV[6]), AV[7]); \
    float g2 = fminf(fminf(fminf(AV[8], AV[9]), AV[10]), AV[11]); \
    float g3 = fminf(fminf(fminf(AV[12], AV[13]), AV[14]), AV[15]); \
    d2x = fminf(d2x, fmaxf(d1, g0)); grp1 = (g0 < d1) ? (cb + 0) : grp1; d1 = fminf(d1, g0); \
    d2x = fminf(d2x, fmaxf(d1, g1)); grp1 = (g1 < d1) ? (cb + 8) : grp1; d1 = fminf(d1, g1); \
    d2x = fminf(d2x, fmaxf(d1, g2)); grp1 = (g2 < d1) ? (cb + 16) : grp1; d1 = fminf(d1, g2); \
    d2x = fminf(d2x, fmaxf(d1, g3)); grp1 = (g3 < d1) ? (cb + 24) : grp1; d1 = fminf(d1, g3); }

#define MFMA9(TB, AOUT) { \
    bf16x8 eh0 = ldfrag16(TB); \
    bf16x8 eh1 = ldfrag16((TB) + 512); \
    bf16x8 eh2 = ldfrag16((TB) + 1024); \
    bf16x8 el0 = ldfrag16((TB) + 1536); \
    bf16x8 el1 = ldfrag16((TB) + 2048); \
    bf16x8 el2 = ldfrag16((TB) + 2560); \
    AOUT = __builtin_amdgcn_mfma_f32_32x32x16_bf16(eh0, xh[0], zacc, 0, 0, 0); \
    AOUT = __builtin_amdgcn_mfma_f32_32x32x16_bf16(eh0, xl[0], AOUT, 0, 0, 0); \
    AOUT = __builtin_amdgcn_mfma_f32_32x32x16_bf16(el0, xh[0], AOUT, 0, 0, 0); \
    AOUT = __builtin_amdgcn_mfma_f32_32x32x16_bf16(eh1, xh[1], AOUT, 0, 0, 0); \
    AOUT = __builtin_amdgcn_mfma_f32_32x32x16_bf16(eh1, xl[1], AOUT, 0, 0, 0); \
    AOUT = __builtin_amdgcn_mfma_f32_32x32x16_bf16(el1, xh[1], AOUT, 0, 0, 0); \
    AOUT = __builtin_amdgcn_mfma_f32_32x32x16_bf16(eh2, xh[2], AOUT, 0, 0, 0); \
    AOUT = __builtin_amdgcn_mfma_f32_32x32x16_bf16(eh2, xl[2], AOUT, 0, 0, 0); \
    AOUT = __builtin_amdgcn_mfma_f32_32x32x16_bf16(el2, xh[2], AOUT, 0, 0, 0); }

  int cur = 0;
#pragma unroll 1
  for (int ch = 0; ch < NCH; ++ch) {
    if (ch + 1 < NCH) {
      STAGE(cur ^ 1, ch + 1)
      asm volatile("s_waitcnt vmcnt(3)" ::: "memory");  // chunk ch done; next 3 in flight
    } else {
      asm volatile("s_waitcnt vmcnt(0)" ::: "memory");
    }
    __builtin_amdgcn_s_barrier();
    {
      const unsigned short* tb0 = &sbuf[cur][lane * 8];
      f32x16 a0;
      MFMA9(tb0, a0)
      TRACKG(a0, ch * 2)
      const unsigned short* tb1 = &sbuf[cur][PK_T + lane * 8];
      f32x16 a1;
      MFMA9(tb1, a1)
      TRACKG(a1, ch * 2 + 1)
    }
    __builtin_amdgcn_s_barrier();   // all waves done reading before next overwrite
    cur ^= 1;
  }

  // ---- end phase: np-exact rescore of the winning GROUP's 4 codes
  float bd = INFINITY;
  int bi = CB;
#pragma unroll
  for (int j = 0; j < 4; ++j) {
    int c = grp1 + j;
    float d = npd_calc(x, etg + (size_t)c * KD, e2g[c], x2np);
    if (d < bd) { bd = d; bi = c; }
  }
  float dd2x = fmaf(2.f, d2x, x2np);

  // cross-half merge ((d,c) order; both bd are np-exact)
  {
    float od = __shfl_xor(bd, 32);
    int oi = __shfl_xor(bi, 32);
    float odd2x = __shfl_xor(dd2x, 32);
    if (od < bd || (od == bd && oi < bi)) { bd = od; bi = oi; }
    dd2x = fminf(dd2x, odd2x);
  }
  bool flag = dd2x < bd + BAND_D;  // another group might np-beat the winner

  // ---- rare wave-level fallback: exact top-3 rescan from GLOBAL epack (r13 logic)
  if (__any(flag)) {
    float rd1 = INFINITY, rd2 = INFINITY, rd3 = INFINITY;
    int ri1 = 0, ri2 = 0, ri3 = 0;
#define INS3(V, C) { \
      bool u1 = (V) < rd1, u2 = (V) < rd2, u3 = (V) < rd3; \
      rd3 = u2 ? rd2 : (u3 ? (V) : rd3); ri3 = u2 ? ri2 : (u3 ? (C) : ri3); \
      rd2 = u1 ? rd1 : (u2 ? (V) : rd2); ri2 = u1 ? ri1 : (u2 ? (C) : ri2); \
      rd1 = u1 ? (V) : rd1;              ri1 = u1 ? (C) : ri1; }
#pragma unroll 1
    for (int tile = 0; tile < 32; ++tile) {
      const unsigned short* tb = egrp + (size_t)tile * PK_T + lane * 8;
      f32x16 a;
      MFMA9(tb, a)
      {
        float gm0 = fminf(fminf(a[0], a[1]), fminf(a[2], a[3]));
        float gm1 = fminf(fminf(a[4], a[5]), fminf(a[6], a[7]));
        float gm2 = fminf(fminf(a[8], a[9]), fminf(a[10], a[11]));
        float gm3 = fminf(fminf(a[12], a[13]), fminf(a[14], a[15]));
        float tmin = fminf(fminf(gm0, gm1), fminf(gm2, gm3));
        if (tmin < rd3) {
          int cb = tile * 32 + 4 * gg;
          if (gm0 < rd3) { INS3(a[0], cb + 0) INS3(a[1], cb + 1) INS3(a[2], cb + 2) INS3(a[3], cb + 3) }
          if (gm1 < rd3) { INS3(a[4], cb + 8) INS3(a[5], cb + 9) INS3(a[6], cb + 10) INS3(a[7], cb + 11) }
          if (gm2 < rd3) { INS3(a[8], cb + 16) INS3(a[9], cb + 17) INS3(a[10], cb + 18) INS3(a[11], cb + 19) }
          if (gm3 < rd3) { INS3(a[12], cb + 24) INS3(a[13], cb + 25) INS3(a[14], cb + 26) INS3(a[15], cb + 27) }
        }
      }
    }
    // r13 end phase (verified): band rescore + cross-half merge with race check
    float dd1 = fmaf(2.f, rd1, x2np);
    float dd2 = fmaf(2.f, rd2, x2np);
    float dd3 = fmaf(2.f, rd3, x2np);
    bd = dd1; bi = ri1;
    bool exact = false;
    {
      bool need2 = dd2 < dd1 + BAND_D;
      bool need3 = dd3 < dd1 + BAND_D;
      if (need2 || need3) {
        int cA = ri1;
        int cB = need2 ? ri2 : 0x7fffffff;
        int cC = need3 ? ri3 : 0x7fffffff;
        int t;
        if (cA > cB) { t = cA; cA = cB; cB = t; }
        if (cB > cC) { t = cB; cB = cC; cC = t; }
        if (cA > cB) { t = cA; cA = cB; cB = t; }
        bd = INFINITY; bi = CB;
        if (cA < CB) { float d = npd_calc(x, etg + (size_t)cA * KD, e2g[cA], x2np); if (d < bd) { bd = d; bi = cA; } }
        if (cB < CB) { float d = npd_calc(x, etg + (size_t)cB * KD, e2g[cB], x2np); if (d < bd) { bd = d; bi = cB; } }
        if (cC < CB) { float d = npd_calc(x, etg + (size_t)cC * KD, e2g[cC], x2np); if (d < bd) { bd = d; bi = cC; } }
        exact = true;
      }
    }
    {
      float od = __shfl_xor(bd, 32);
      bool race = fabsf(bd - od) < BAND_D;
      if (race && !exact) bd = npd_calc(x, etg + (size_t)bi * KD, e2g[bi], x2np);
      float od2 = __shfl_xor(bd, 32);
      int oi = __shfl_xor(bi, 32);
      if (od2 < bd || (od2 == bd && oi < bi)) { bd = od2; bi = oi; }
    }
  }

  // ---- epilogue: STE write + loss partial, static k-halves per gg
  const float4* eb4 = (const float4*)(etg + (size_t)bi * KD);
  float* op = out + (size_t)n * ZN + (size_t)g * ZG + tt;
  float ls = 0.f;
  if (gg == 0) {
#pragma unroll
    for (int p = 0; p < 5; ++p) {
      float4 v = eb4[p];
      int k = 4 * p;
      float e0 = __fsub_rn(v.x, x[k + 0]); ls = fmaf(e0, e0, ls); op[(size_t)(k + 0) * TP] = __fadd_rn(x[k + 0], e0);
      float e1 = __fsub_rn(v.y, x[k + 1]); ls = fmaf(e1, e1, ls); op[(size_t)(k + 1) * TP] = __fadd_rn(x[k + 1], e1);
      float e2v = __fsub_rn(v.z, x[k + 2]); ls = fmaf(e2v, e2v, ls); op[(size_t)(k + 2) * TP] = __fadd_rn(x[k + 2], e2v);
      float e3 = __fsub_rn(v.w, x[k + 3]); ls = fmaf(e3, e3, ls); op[(size_t)(k + 3) * TP] = __fadd_rn(x[k + 3], e3);
    }
  } else {
#pragma unroll
    for (int p = 5; p < 10; ++p) {
      float4 v = eb4[p];
      int k = 4 * p;
      float e0 = __fsub_rn(v.x, x[k + 0]); ls = fmaf(e0, e0, ls); op[(size_t)(k + 0) * TP] = __fadd_rn(x[k + 0], e0);
      float e1 = __fsub_rn(v.y, x[k + 1]); ls = fmaf(e1, e1, ls); op[(size_t)(k + 1) * TP] = __fadd_rn(x[k + 1], e1);
      float e2v = __fsub_rn(v.z, x[k + 2]); ls = fmaf(e2v, e2v, ls); op[(size_t)(k + 2) * TP] = __fadd_rn(x[k + 2], e2v);
      float e3 = __fsub_rn(v.w, x[k + 3]); ls = fmaf(e3, e3, ls); op[(size_t)(k + 3) * TP] = __fadd_rn(x[k + 3], e3);
    }
  }

  // ---- deterministic segmented block reduce (block straddles <=1 n boundary)
  const int n_lo = (bb * RPB) / TP;
  r0s[tid] = (n == n_lo) ? ls : 0.f;
  r1s[tid] = (n == n_lo) ? 0.f : ls;
  __syncthreads();
  for (int s = THREADS / 2; s > 0; s >>= 1) {
    if (tid < s) {
      r0s[tid] += r0s[tid + s];
      r1s[tid] += r1s[tid + s];
    }
    __syncthreads();
  }
  if (tid == 0) {
    partials[((size_t)g * NBLK + bb) * 2 + 0] = r0s[0];
    partials[((size_t)g * NBLK + bb) * 2 + 1] = r1s[0];
  }
}

// ---- final: fixed-order reduction of per-block partials -> vq_loss[n]
__global__ void loss_kernel(const float* __restrict__ partials,
                            float* __restrict__ vq) {
  int n = threadIdx.x;
  if (n >= NB) return;
  float acc = 0.f;
  for (int g = 0; g < NG; ++g) {
    float s = 0.f;
    int b0 = (n * TP) / RPB;
    int b1 = ((n + 1) * TP - 1) / RPB;
    for (int b = b0; b <= b1; ++b) {
      int n_lo = (b * RPB) / TP;
      s += partials[((size_t)g * NBLK + b) * 2 + ((n == n_lo) ? 0 : 1)];
    }
    acc += 0.25f * (s / 80000.0f);
  }
  vq[n] = acc / 6.0f;
}

extern "C" void kernel_launch(void* const* d_in, const int* in_sizes, int n_in,
                              void* d_out, int out_size, void* d_ws, size_t ws_size,
                              hipStream_t stream) {
  const float* z = (const float*)d_in[0];
  const float* emb = (const float*)d_in[1];
  float* out = (float*)d_out;

  float* et = (float*)d_ws;                          // 983,040 B
  float* e2 = et + (size_t)NG * CB * KD;             // 24,576 B
  float* partials = e2 + (size_t)NG * CB;            // 24,000 B
  unsigned short* epack = (unsigned short*)((char*)d_ws + 1031680);  // 1,179,648 B

  prep_kernel<<<dim3(CB / 256, NG), 256, 0, stream>>>(emb, et, e2, epack);
  vq_kernel<<<dim3(NBLK, NG), THREADS, 0, stream>>>(z, et, e2, epack, out, partials);
  loss_kernel<<<1, 64, 0, stream>>>(partials, out + (size_t)NB * 60 * 8000);
}